// Round 20
// baseline (337.469 us; speedup 1.0000x reference)
//
#include <hip/hip_runtime.h>
#include <hip/hip_bf16.h>
#include <cstdint>
#include <cstddef>

#define NROWS 131072
#define DDIM  1024
#define LDIM  128
#define BSEG  64
#define FIX2  281474976710656.0   // 2^48

typedef float f32x4 __attribute__((ext_vector_type(4)));
typedef short short8 __attribute__((ext_vector_type(8)));

__device__ inline unsigned short f2bf(float f) {
    union { float f; unsigned u; } x; x.f = f;
    unsigned u = x.u + 0x7fffu + ((x.u >> 16) & 1u);
    return (unsigned short)(u >> 16);
}

__device__ inline int lower_bound_dev(const int* __restrict__ arr, int n, int v) {
    int lo = 0, hi = n;
    while (lo < hi) { int mid = (lo + hi) >> 1; if (arr[mid] < v) lo = mid + 1; else hi = mid; }
    return lo;
}

// ---------------- W pre-convert: f32 -> bf16, fragment-major packed layout (8 waves) ----
// Wave w owns cols: nfi=0 -> Wa rows w*16+rA ; nfi=1 -> Wb rows w*16+rA.
// frag f = ((kt*2+kk)*8 + w)*2 + nfi ; byte = f*1024 + lane*16 + inner ; lane = kl*16 + rA.
__global__ void wconv_kernel(const float* __restrict__ Wa, const float* __restrict__ Wb,
                             unsigned short* __restrict__ wpre) {
    int n  = blockIdx.x;                 // 0..255 (0..127 Wa, 128..255 Wb)
    int kt = threadIdx.x >> 4;           // 0..15
    int q  = threadIdx.x & 15;           // k quad: k = kt*64 + q*4
    const float* wrow = (n < LDIM) ? (Wa + (size_t)n * DDIM)
                                   : (Wb + (size_t)(n - LDIM) * DDIM);
    float4 v = *(const float4*)(wrow + kt * 64 + q * 4);
    ushort4 h;
    h.x = f2bf(v.x); h.y = f2bf(v.y); h.z = f2bf(v.z); h.w = f2bf(v.w);
    int w, nfi, rA;
    if (n < LDIM) { w = n >> 4; nfi = 0; rA = n & 15; }
    else { int m = n - LDIM; w = m >> 4; nfi = 1; rA = m & 15; }
    int kk    = q >> 3;
    int e     = (q & 7) * 4;             // elem offset within kk-half (0..28)
    int kl    = e >> 3;
    int inner = (e & 7) * 2;             // byte offset within lane chunk
    int lane  = kl * 16 + rA;
    int f     = ((kt * 2 + kk) * 8 + w) * 2 + nfi;
    *(ushort4*)((char*)wpre + f * 1024 + lane * 16 + inner) = h;
}

// ---------------- fused GEMM + post-norm + gated score + segment partial sums ----------------
// 512 threads (8 waves), BM=64, per-wave output 64x32 (acc[4][2] = 32 AGPR).
// FOUR K-tiles per barrier (each 32KB LDS buffer = 4 x 8KB sub-tiles): 64
// independent MFMAs + 32 ds_reads per wave between barriers; barriers 16 -> 4.
// Distance-1 av prefetch (single 8xfloat4 set): issued end of super-iter st,
// staged end of st+1 (~7000 cy cover, 8x HBM latency). NT output stores.
__global__ __launch_bounds__(512, 4)
void gemm_kernel(const float* __restrict__ feat, const unsigned short* __restrict__ wpre,
                 const float* __restrict__ ba, const float* __restrict__ bb,
                 const float* __restrict__ Wc, const float* __restrict__ bc,
                 const int* __restrict__ batch,
                 float* __restrict__ nf_out, float* __restrict__ s_out,
                 unsigned long long* __restrict__ acc64)
{
    __shared__ __align__(16) char smem[68352];
    // bufs: [0,32768) and [32768,65536); subtile t of a buf at +t*8192
    float* invA_l = (float*)(smem + 65536);   // [64]
    float* part   = (float*)(smem + 65792);   // [8][64]
    float* u_row  = (float*)(smem + 67840);   // [64]
    int*   seg_l  = (int*)(smem + 68096);     // [64]

    const int tid  = threadIdx.x;
    const int w    = tid >> 6;     // wave 0..7
    const int lane = tid & 63;
    const int rblk = blockIdx.x * 64;
    const int sr   = tid >> 3;     // staging row 0..63
    const int sc8  = tid & 7;      // staging col-eighth 0..7

    if (tid < 64) seg_l[tid] = batch[rblk + tid];

    const float4* rowp4 = (const float4*)(feat + (size_t)(rblk + sr) * DDIM);

    f32x4 acc[4][2];
    #pragma unroll
    for (int i = 0; i < 4; ++i)
        #pragma unroll
        for (int j = 0; j < 2; ++j)
            acc[i][j] = (f32x4){0.f, 0.f, 0.f, 0.f};

    const int rA  = lane & 15;
    const int kl  = lane >> 4;
    const int swz = (lane & 7) << 4;
    const char* wsrc = (const char*)wpre + w * 2048 + lane * 16;

    float4 av[8];   // tile t2, half j -> av[t2*2+j]; all indices compile-time
    float sq = 0.f;

    // ---- prologue: stage tiles 0..3 direct into buf0; issue av <- tiles 4..7
    #pragma unroll
    for (int t = 0; t < 4; ++t) {
        #pragma unroll
        for (int j = 0; j < 2; ++j) {
            int cf = sc8 + j * 8;
            float4 v = rowp4[t * 16 + cf];
            sq += v.x * v.x + v.y * v.y + v.z * v.z + v.w * v.w;
            union { ushort4 h; __hip_bfloat162 b2[2]; } cv;
            cv.b2[0] = __float22bfloat162_rn(make_float2(v.x, v.y));
            cv.b2[1] = __float22bfloat162_rn(make_float2(v.z, v.w));
            *(ushort4*)(smem + t * 8192 + ((sr * 128 + cf * 8) ^ ((sr & 7) << 4))) = cv.h;
        }
    }
    #pragma unroll
    for (int t = 0; t < 4; ++t) {
        av[t * 2 + 0] = rowp4[(4 + t) * 16 + sc8];
        av[t * 2 + 1] = rowp4[(4 + t) * 16 + sc8 + 8];
    }
    __syncthreads();

    #pragma unroll
    for (int st = 0; st < 4; ++st) {
        const int cur = st & 1;
        const char* Abuf = smem + cur * 32768;
        // ---- 4 sub-tiles: per kt, W frags then MFMAs (waits drain only old loads)
        #pragma unroll
        for (int kt4 = 0; kt4 < 4; ++kt4) {
            const int kt = st * 4 + kt4;
            short8 wf[4];
            #pragma unroll
            for (int q = 0; q < 4; ++q)
                wf[q] = *(const short8*)(wsrc + (size_t)kt * 32768 + (q >> 1) * 16384 + (q & 1) * 1024);
            #pragma unroll
            for (int kk = 0; kk < 2; ++kk) {
                int koff = (kk * 64 + kl * 16) ^ swz;
                #pragma unroll
                for (int mf = 0; mf < 4; ++mf) {
                    short8 af = *(const short8*)(Abuf + kt4 * 8192 + (mf * 16 + rA) * 128 + koff);
                    #pragma unroll
                    for (int nfi = 0; nfi < 2; ++nfi)
                        acc[mf][nfi] = __builtin_amdgcn_mfma_f32_16x16x32_bf16(
                            af, wf[kk * 2 + nfi], acc[mf][nfi], 0, 0, 0);
                }
            }
        }
        // ---- stage av (tiles (st+1)*4..) into the other buffer, then reissue av
        if (st < 3) {
            char* Ab2 = smem + (cur ^ 1) * 32768;
            #pragma unroll
            for (int t = 0; t < 4; ++t) {
                #pragma unroll
                for (int j = 0; j < 2; ++j) {
                    int cf = sc8 + j * 8;
                    float4 v = av[t * 2 + j];
                    sq += v.x * v.x + v.y * v.y + v.z * v.z + v.w * v.w;
                    union { ushort4 h; __hip_bfloat162 b2[2]; } cv;
                    cv.b2[0] = __float22bfloat162_rn(make_float2(v.x, v.y));
                    cv.b2[1] = __float22bfloat162_rn(make_float2(v.z, v.w));
                    *(ushort4*)(Ab2 + t * 8192 + ((sr * 128 + cf * 8) ^ ((sr & 7) << 4))) = cv.h;
                }
            }
            if (st < 2) {
                #pragma unroll
                for (int t = 0; t < 4; ++t) {
                    av[t * 2 + 0] = rowp4[((st + 2) * 4 + t) * 16 + sc8];
                    av[t * 2 + 1] = rowp4[((st + 2) * 4 + t) * 16 + sc8 + 8];
                }
            }
        }
        __syncthreads();
    }

    // ---- finalize invA (8 staging threads per row hold partials; reduce over sc8)
    sq += __shfl_xor(sq, 1, 64);
    sq += __shfl_xor(sq, 2, 64);
    sq += __shfl_xor(sq, 4, 64);
    if (sc8 == 0) invA_l[sr] = 1.f / fmaxf(sqrtf(sq), 1e-12f);
    __syncthreads();

    // ---- epilogue-1: gated score, lane-local (wave w owns Wa col w*16+rA and Wb col w*16+rA)
    {
        int l0 = w * 16 + rA;
        float ba0 = ba[l0], bb0 = bb[l0], wc0 = Wc[l0];
        float vals[4][4];
        #pragma unroll
        for (int mf = 0; mf < 4; ++mf)
            #pragma unroll
            for (int reg = 0; reg < 4; ++reg) {
                int r = mf * 16 + kl * 4 + reg;
                float ia = invA_l[r];
                float pa0 = acc[mf][0][reg] * ia + ba0;
                float pb0 = acc[mf][1][reg] * ia + bb0;
                float a0 = 1.f / (1.f + __expf(-pa0));
                float b0 = 1.f - 2.f / (1.f + __expf(2.f * pb0));
                vals[mf][reg] = a0 * b0 * wc0;
            }
        #pragma unroll
        for (int mf = 0; mf < 4; ++mf)
            #pragma unroll
            for (int reg = 0; reg < 4; ++reg) {
                float v = vals[mf][reg];
                v += __shfl_xor(v, 1, 64);
                v += __shfl_xor(v, 2, 64);
                v += __shfl_xor(v, 4, 64);
                v += __shfl_xor(v, 8, 64);
                vals[mf][reg] = v;
            }
        if (rA == 0) {
            #pragma unroll
            for (int mf = 0; mf < 4; ++mf)
                #pragma unroll
                for (int reg = 0; reg < 4; ++reg)
                    part[w * 64 + mf * 16 + kl * 4 + reg] = vals[mf][reg];
        }
    }
    __syncthreads();
    if (tid < 64) {
        float s = part[tid] + part[64 + tid] + part[128 + tid] + part[192 + tid]
                + part[256 + tid] + part[320 + tid] + part[384 + tid] + part[448 + tid] + bc[0];
        u_row[tid] = __expf(s);
        __builtin_nontemporal_store(s, &s_out[rblk + tid]);
    }
    __syncthreads();

    // ---- epilogue-2: nf write (x*invA, NON-TEMPORAL) + per-segment weighted partials
    {
        const int col = tid & 255;
        const int grp = tid >> 8;
        const float4* __restrict__ fbase = (const float4*)(feat + (size_t)rblk * DDIM);
        f32x4*        __restrict__ nbase = (f32x4*)(nf_out + (size_t)rblk * DDIM);
        float ax = 0.f, ay = 0.f, az = 0.f, aw = 0.f;
        int curseg = seg_l[grp];
        for (int rr = 0; rr < 8; ++rr) {
            int r0 = rr * 8 + grp;
            float4 v0 = fbase[(r0 + 0) * 256 + col];
            float4 v1 = fbase[(r0 + 2) * 256 + col];
            float4 v2 = fbase[(r0 + 4) * 256 + col];
            float4 v3 = fbase[(r0 + 6) * 256 + col];
            #pragma unroll
            for (int j = 0; j < 4; ++j) {
                int r = r0 + j * 2;
                float4 v = (j == 0) ? v0 : (j == 1) ? v1 : (j == 2) ? v2 : v3;
                int sg = seg_l[r];
                if (sg != curseg) {
                    unsigned long long* dst = acc64 + (size_t)curseg * DDIM + col * 4;
                    atomicAdd(&dst[0], (unsigned long long)(long long)((double)ax * FIX2));
                    atomicAdd(&dst[1], (unsigned long long)(long long)((double)ay * FIX2));
                    atomicAdd(&dst[2], (unsigned long long)(long long)((double)az * FIX2));
                    atomicAdd(&dst[3], (unsigned long long)(long long)((double)aw * FIX2));
                    ax = ay = az = aw = 0.f;
                    curseg = sg;
                }
                float ia = invA_l[r];
                float u  = u_row[r];
                v.x *= ia; v.y *= ia; v.z *= ia; v.w *= ia;
                f32x4 vv = {v.x, v.y, v.z, v.w};
                __builtin_nontemporal_store(vv, &nbase[r * 256 + col]);
                ax += u * v.x; ay += u * v.y; az += u * v.z; aw += u * v.w;
            }
        }
        unsigned long long* dst = acc64 + (size_t)curseg * DDIM + col * 4;
        atomicAdd(&dst[0], (unsigned long long)(long long)((double)ax * FIX2));
        atomicAdd(&dst[1], (unsigned long long)(long long)((double)ay * FIX2));
        atomicAdd(&dst[2], (unsigned long long)(long long)((double)az * FIX2));
        atomicAdd(&dst[3], (unsigned long long)(long long)((double)aw * FIX2));
    }
}

// ---------------- softmax per segment, in place; also emits per-segment M and D ----------------
__global__ void softmax_kernel(const int* __restrict__ batch, float* __restrict__ score,
                               float* __restrict__ smax, float* __restrict__ ssum) {
    int b = blockIdx.x;
    int tid = threadIdx.x;
    int start = lower_bound_dev(batch, NROWS, b);
    int end   = lower_bound_dev(batch, NROWS, b + 1);
    __shared__ float red[4];
    __shared__ float bm, bd;

    float m = -INFINITY;
    for (int i = start + tid; i < end; i += 256) m = fmaxf(m, score[i]);
    #pragma unroll
    for (int k = 1; k < 64; k <<= 1) m = fmaxf(m, __shfl_xor(m, k, 64));
    if ((tid & 63) == 0) red[tid >> 6] = m;
    __syncthreads();
    if (tid == 0) bm = fmaxf(fmaxf(red[0], red[1]), fmaxf(red[2], red[3]));
    __syncthreads();
    float M = bm;

    float sum = 0.f;
    for (int i = start + tid; i < end; i += 256) sum += __expf(score[i] - M);
    #pragma unroll
    for (int k = 1; k < 64; k <<= 1) sum += __shfl_xor(sum, k, 64);
    if ((tid & 63) == 0) red[tid >> 6] = sum;
    __syncthreads();
    if (tid == 0) { bd = red[0] + red[1] + red[2] + red[3]; smax[b] = bm; ssum[b] = bd; }
    __syncthreads();
    float invD = 1.f / bd;

    for (int i = start + tid; i < end; i += 256)
        score[i] = __expf(score[i] - M) * invD;
}

// ---------------- finalize: out = fix2float(acc64) / (e^M * D) ----------------
__global__ void finalize_kernel(const unsigned long long* __restrict__ acc64,
                                const float* __restrict__ smax, const float* __restrict__ ssum,
                                float* __restrict__ out) {
    int i = blockIdx.x * 256 + threadIdx.x;
    int b = i >> 10;
    double denom = exp((double)smax[b]) * (double)ssum[b];
    out[i] = (float)(((double)(long long)acc64[i]) * (1.0 / FIX2) / denom);
}

extern "C" void kernel_launch(void* const* d_in, const int* in_sizes, int n_in,
                              void* d_out, int out_size, void* d_ws, size_t ws_size,
                              hipStream_t stream) {
    const float* feat  = (const float*)d_in[0];
    const int*   batch = (const int*)d_in[1];
    const float* Wa = (const float*)d_in[2];
    const float* ba = (const float*)d_in[3];
    const float* Wb = (const float*)d_in[4];
    const float* bb = (const float*)d_in[5];
    const float* Wc = (const float*)d_in[6];
    const float* bc = (const float*)d_in[7];

    float* out_seg = (float*)d_out;                  // B*D
    float* score   = out_seg + (size_t)BSEG * DDIM;  // N (raw s, then softmax in place)
    float* nf      = score + NROWS;                  // N*D

    unsigned short*     wpre  = (unsigned short*)d_ws;                       // 512 KB
    unsigned long long* acc64 = (unsigned long long*)((char*)d_ws + 524288); // 512 KB
    // smax/ssum overlay the wpre region: written after gemm is done with wpre
    float* smax = (float*)d_ws;
    float* ssum = smax + BSEG;

    hipMemsetAsync(acc64, 0, (size_t)BSEG * DDIM * 8, stream);
    wconv_kernel<<<256, 256, 0, stream>>>(Wa, Wb, wpre);
    gemm_kernel<<<NROWS / 64, 512, 0, stream>>>(feat, wpre, ba, bb, Wc, bc, batch,
                                                nf, score, acc64);
    softmax_kernel<<<BSEG, 256, 0, stream>>>(batch, score, smax, ssum);
    finalize_kernel<<<BSEG * DDIM / 256, 256, 0, stream>>>(acc64, smax, ssum, out_seg);
}

// Round 21
// 328.784 us; speedup vs baseline: 1.0264x; 1.0264x over previous
//
#include <hip/hip_runtime.h>
#include <hip/hip_bf16.h>
#include <cstdint>
#include <cstddef>

#define NROWS 131072
#define DDIM  1024
#define LDIM  128
#define BSEG  64
#define FIX2  281474976710656.0   // 2^48

typedef float f32x4 __attribute__((ext_vector_type(4)));
typedef short short8 __attribute__((ext_vector_type(8)));

__device__ inline unsigned short f2bf(float f) {
    union { float f; unsigned u; } x; x.f = f;
    unsigned u = x.u + 0x7fffu + ((x.u >> 16) & 1u);
    return (unsigned short)(u >> 16);
}

__device__ inline int lower_bound_dev(const int* __restrict__ arr, int n, int v) {
    int lo = 0, hi = n;
    while (lo < hi) { int mid = (lo + hi) >> 1; if (arr[mid] < v) lo = mid + 1; else hi = mid; }
    return lo;
}

// ---------------- W pre-convert: f32 -> bf16, fragment-major packed layout (8 waves) ----
// Wave w owns cols: nfi=0 -> Wa rows w*16+rA ; nfi=1 -> Wb rows w*16+rA.
// frag f = ((kt*2+kk)*8 + w)*2 + nfi ; byte = f*1024 + lane*16 + inner ; lane = kl*16 + rA.
__global__ void wconv_kernel(const float* __restrict__ Wa, const float* __restrict__ Wb,
                             unsigned short* __restrict__ wpre) {
    int n  = blockIdx.x;                 // 0..255 (0..127 Wa, 128..255 Wb)
    int kt = threadIdx.x >> 4;           // 0..15
    int q  = threadIdx.x & 15;           // k quad: k = kt*64 + q*4
    const float* wrow = (n < LDIM) ? (Wa + (size_t)n * DDIM)
                                   : (Wb + (size_t)(n - LDIM) * DDIM);
    float4 v = *(const float4*)(wrow + kt * 64 + q * 4);
    ushort4 h;
    h.x = f2bf(v.x); h.y = f2bf(v.y); h.z = f2bf(v.z); h.w = f2bf(v.w);
    int w, nfi, rA;
    if (n < LDIM) { w = n >> 4; nfi = 0; rA = n & 15; }
    else { int m = n - LDIM; w = m >> 4; nfi = 1; rA = m & 15; }
    int kk    = q >> 3;
    int e     = (q & 7) * 4;             // elem offset within kk-half (0..28)
    int kl    = e >> 3;
    int inner = (e & 7) * 2;             // byte offset within lane chunk
    int lane  = kl * 16 + rA;
    int f     = ((kt * 2 + kk) * 8 + w) * 2 + nfi;
    *(ushort4*)((char*)wpre + f * 1024 + lane * 16 + inner) = h;
}

// ---------------- fused GEMM + post-norm + gated score + segment partial sums ----------------
// 512 threads (8 waves), BM=64, per-wave output 64x32 (acc[4][2] = 32 AGPR).
// TWO K-tiles per barrier (each 16KB LDS buffer holds 2 x 8KB sub-tiles): 32
// independent MFMAs + 16 ds_reads between barriers; barrier count 16 -> 8.
// Issue order per super-iter: wf0 -> MFMA0 -> wf1 -> MFMA1 -> av2 -> stage -> barrier
// (each MFMA batch's vmcnt wait leaves the HBM prefetch in flight). NT output stores.
__global__ __launch_bounds__(512, 6)
void gemm_kernel(const float* __restrict__ feat, const unsigned short* __restrict__ wpre,
                 const float* __restrict__ ba, const float* __restrict__ bb,
                 const float* __restrict__ Wc, const float* __restrict__ bc,
                 const int* __restrict__ batch,
                 float* __restrict__ nf_out, float* __restrict__ s_out,
                 unsigned long long* __restrict__ acc64)
{
    __shared__ __align__(16) char smem[35584];
    float* invA_l = (float*)(smem + 32768);   // [64]
    float* part   = (float*)(smem + 33024);   // [8][64]
    float* u_row  = (float*)(smem + 35072);   // [64]
    int*   seg_l  = (int*)(smem + 35328);     // [64]

    const int tid  = threadIdx.x;
    const int w    = tid >> 6;     // wave 0..7
    const int lane = tid & 63;
    const int rblk = blockIdx.x * 64;
    const int sr   = tid >> 3;     // staging row 0..63
    const int sc8  = tid & 7;      // staging col-eighth 0..7

    if (tid < 64) seg_l[tid] = batch[rblk + tid];

    const float4* rowp4 = (const float4*)(feat + (size_t)(rblk + sr) * DDIM);

    f32x4 acc[4][2];
    #pragma unroll
    for (int i = 0; i < 4; ++i)
        #pragma unroll
        for (int j = 0; j < 2; ++j)
            acc[i][j] = (f32x4){0.f, 0.f, 0.f, 0.f};

    const int rA  = lane & 15;
    const int kl  = lane >> 4;
    const int swz = (lane & 7) << 4;
    const char* wsrc = (const char*)wpre + w * 2048 + lane * 16;

    float4 av1_0, av1_1, av1_2, av1_3, av2_0, av2_1, av2_2, av2_3;
    float sq = 0.f;

    // ---- prologue: stage tiles 0,1 into buf0 halves; issue loads for tiles 2,3
    #pragma unroll
    for (int t = 0; t < 2; ++t) {
        #pragma unroll
        for (int j = 0; j < 2; ++j) {
            int cf = sc8 + j * 8;
            float4 v = rowp4[t * 16 + cf];
            sq += v.x * v.x + v.y * v.y + v.z * v.z + v.w * v.w;
            union { ushort4 h; __hip_bfloat162 b2[2]; } cv;
            cv.b2[0] = __float22bfloat162_rn(make_float2(v.x, v.y));
            cv.b2[1] = __float22bfloat162_rn(make_float2(v.z, v.w));
            *(ushort4*)(smem + t * 8192 + ((sr * 128 + cf * 8) ^ ((sr & 7) << 4))) = cv.h;
        }
    }
    av1_0 = rowp4[32 + sc8];
    av1_1 = rowp4[32 + sc8 + 8];
    av1_2 = rowp4[48 + sc8];
    av1_3 = rowp4[48 + sc8 + 8];
    __syncthreads();

    #pragma unroll
    for (int st = 0; st < 8; ++st) {
        const int cur = st & 1;
        const char* Abuf = smem + cur * 16384;
        // ---- sub-tile 0: W frags then MFMA (vmcnt wait covers only these 4 loads)
        {
            const int kt = st * 2;
            short8 wf[4];
            #pragma unroll
            for (int q = 0; q < 4; ++q)
                wf[q] = *(const short8*)(wsrc + (size_t)kt * 32768 + (q >> 1) * 16384 + (q & 1) * 1024);
            #pragma unroll
            for (int kk = 0; kk < 2; ++kk) {
                int koff = (kk * 64 + kl * 16) ^ swz;
                #pragma unroll
                for (int mf = 0; mf < 4; ++mf) {
                    short8 af = *(const short8*)(Abuf + (mf * 16 + rA) * 128 + koff);
                    #pragma unroll
                    for (int nfi = 0; nfi < 2; ++nfi)
                        acc[mf][nfi] = __builtin_amdgcn_mfma_f32_16x16x32_bf16(
                            af, wf[kk * 2 + nfi], acc[mf][nfi], 0, 0, 0);
                }
            }
        }
        // ---- sub-tile 1
        {
            const int kt = st * 2 + 1;
            short8 wf[4];
            #pragma unroll
            for (int q = 0; q < 4; ++q)
                wf[q] = *(const short8*)(wsrc + (size_t)kt * 32768 + (q >> 1) * 16384 + (q & 1) * 1024);
            #pragma unroll
            for (int kk = 0; kk < 2; ++kk) {
                int koff = (kk * 64 + kl * 16) ^ swz;
                #pragma unroll
                for (int mf = 0; mf < 4; ++mf) {
                    short8 af = *(const short8*)(Abuf + 8192 + (mf * 16 + rA) * 128 + koff);
                    #pragma unroll
                    for (int nfi = 0; nfi < 2; ++nfi)
                        acc[mf][nfi] = __builtin_amdgcn_mfma_f32_16x16x32_bf16(
                            af, wf[kk * 2 + nfi], acc[mf][nfi], 0, 0, 0);
                }
            }
        }
        // ---- issue av2: tiles for super-iter st+2 (stays in flight across the barrier)
        if (st < 6) {
            av2_0 = rowp4[(st + 2) * 32 + sc8];
            av2_1 = rowp4[(st + 2) * 32 + sc8 + 8];
            av2_2 = rowp4[(st + 2) * 32 + 16 + sc8];
            av2_3 = rowp4[(st + 2) * 32 + 16 + sc8 + 8];
        }
        // ---- stage av1 (tiles for st+1) into the other buffer
        if (st < 7) {
            char* Ab2 = smem + (cur ^ 1) * 16384;
            #pragma unroll
            for (int t = 0; t < 2; ++t) {
                #pragma unroll
                for (int j = 0; j < 2; ++j) {
                    int cf = sc8 + j * 8;
                    float4 v = (t == 0) ? ((j == 0) ? av1_0 : av1_1)
                                        : ((j == 0) ? av1_2 : av1_3);
                    sq += v.x * v.x + v.y * v.y + v.z * v.z + v.w * v.w;
                    union { ushort4 h; __hip_bfloat162 b2[2]; } cv;
                    cv.b2[0] = __float22bfloat162_rn(make_float2(v.x, v.y));
                    cv.b2[1] = __float22bfloat162_rn(make_float2(v.z, v.w));
                    *(ushort4*)(Ab2 + t * 8192 + ((sr * 128 + cf * 8) ^ ((sr & 7) << 4))) = cv.h;
                }
            }
        }
        __syncthreads();
        av1_0 = av2_0; av1_1 = av2_1; av1_2 = av2_2; av1_3 = av2_3;
    }

    // ---- finalize invA (8 staging threads per row hold partials; reduce over sc8)
    sq += __shfl_xor(sq, 1, 64);
    sq += __shfl_xor(sq, 2, 64);
    sq += __shfl_xor(sq, 4, 64);
    if (sc8 == 0) invA_l[sr] = 1.f / fmaxf(sqrtf(sq), 1e-12f);
    __syncthreads();

    // ---- epilogue-1: gated score, lane-local (wave w owns Wa col w*16+rA and Wb col w*16+rA)
    {
        int l0 = w * 16 + rA;
        float ba0 = ba[l0], bb0 = bb[l0], wc0 = Wc[l0];
        float vals[4][4];
        #pragma unroll
        for (int mf = 0; mf < 4; ++mf)
            #pragma unroll
            for (int reg = 0; reg < 4; ++reg) {
                int r = mf * 16 + kl * 4 + reg;
                float ia = invA_l[r];
                float pa0 = acc[mf][0][reg] * ia + ba0;
                float pb0 = acc[mf][1][reg] * ia + bb0;
                float a0 = 1.f / (1.f + __expf(-pa0));
                float b0 = 1.f - 2.f / (1.f + __expf(2.f * pb0));
                vals[mf][reg] = a0 * b0 * wc0;
            }
        #pragma unroll
        for (int mf = 0; mf < 4; ++mf)
            #pragma unroll
            for (int reg = 0; reg < 4; ++reg) {
                float v = vals[mf][reg];
                v += __shfl_xor(v, 1, 64);
                v += __shfl_xor(v, 2, 64);
                v += __shfl_xor(v, 4, 64);
                v += __shfl_xor(v, 8, 64);
                vals[mf][reg] = v;
            }
        if (rA == 0) {
            #pragma unroll
            for (int mf = 0; mf < 4; ++mf)
                #pragma unroll
                for (int reg = 0; reg < 4; ++reg)
                    part[w * 64 + mf * 16 + kl * 4 + reg] = vals[mf][reg];
        }
    }
    __syncthreads();
    if (tid < 64) {
        float s = part[tid] + part[64 + tid] + part[128 + tid] + part[192 + tid]
                + part[256 + tid] + part[320 + tid] + part[384 + tid] + part[448 + tid] + bc[0];
        u_row[tid] = __expf(s);
        __builtin_nontemporal_store(s, &s_out[rblk + tid]);
    }
    __syncthreads();

    // ---- epilogue-2: nf write (x*invA, NON-TEMPORAL) + per-segment weighted partials
    {
        const int col = tid & 255;
        const int grp = tid >> 8;
        const float4* __restrict__ fbase = (const float4*)(feat + (size_t)rblk * DDIM);
        f32x4*        __restrict__ nbase = (f32x4*)(nf_out + (size_t)rblk * DDIM);
        float ax = 0.f, ay = 0.f, az = 0.f, aw = 0.f;
        int curseg = seg_l[grp];
        for (int rr = 0; rr < 8; ++rr) {
            int r0 = rr * 8 + grp;
            float4 v0 = fbase[(r0 + 0) * 256 + col];
            float4 v1 = fbase[(r0 + 2) * 256 + col];
            float4 v2 = fbase[(r0 + 4) * 256 + col];
            float4 v3 = fbase[(r0 + 6) * 256 + col];
            #pragma unroll
            for (int j = 0; j < 4; ++j) {
                int r = r0 + j * 2;
                float4 v = (j == 0) ? v0 : (j == 1) ? v1 : (j == 2) ? v2 : v3;
                int sg = seg_l[r];
                if (sg != curseg) {
                    unsigned long long* dst = acc64 + (size_t)curseg * DDIM + col * 4;
                    atomicAdd(&dst[0], (unsigned long long)(long long)((double)ax * FIX2));
                    atomicAdd(&dst[1], (unsigned long long)(long long)((double)ay * FIX2));
                    atomicAdd(&dst[2], (unsigned long long)(long long)((double)az * FIX2));
                    atomicAdd(&dst[3], (unsigned long long)(long long)((double)aw * FIX2));
                    ax = ay = az = aw = 0.f;
                    curseg = sg;
                }
                float ia = invA_l[r];
                float u  = u_row[r];
                v.x *= ia; v.y *= ia; v.z *= ia; v.w *= ia;
                f32x4 vv = {v.x, v.y, v.z, v.w};
                __builtin_nontemporal_store(vv, &nbase[r * 256 + col]);
                ax += u * v.x; ay += u * v.y; az += u * v.z; aw += u * v.w;
            }
        }
        unsigned long long* dst = acc64 + (size_t)curseg * DDIM + col * 4;
        atomicAdd(&dst[0], (unsigned long long)(long long)((double)ax * FIX2));
        atomicAdd(&dst[1], (unsigned long long)(long long)((double)ay * FIX2));
        atomicAdd(&dst[2], (unsigned long long)(long long)((double)az * FIX2));
        atomicAdd(&dst[3], (unsigned long long)(long long)((double)aw * FIX2));
    }
}

// ---------------- softmax per segment, in place; also emits per-segment M and D ----------------
__global__ void softmax_kernel(const int* __restrict__ batch, float* __restrict__ score,
                               float* __restrict__ smax, float* __restrict__ ssum) {
    int b = blockIdx.x;
    int tid = threadIdx.x;
    int start = lower_bound_dev(batch, NROWS, b);
    int end   = lower_bound_dev(batch, NROWS, b + 1);
    __shared__ float red[4];
    __shared__ float bm, bd;

    float m = -INFINITY;
    for (int i = start + tid; i < end; i += 256) m = fmaxf(m, score[i]);
    #pragma unroll
    for (int k = 1; k < 64; k <<= 1) m = fmaxf(m, __shfl_xor(m, k, 64));
    if ((tid & 63) == 0) red[tid >> 6] = m;
    __syncthreads();
    if (tid == 0) bm = fmaxf(fmaxf(red[0], red[1]), fmaxf(red[2], red[3]));
    __syncthreads();
    float M = bm;

    float sum = 0.f;
    for (int i = start + tid; i < end; i += 256) sum += __expf(score[i] - M);
    #pragma unroll
    for (int k = 1; k < 64; k <<= 1) sum += __shfl_xor(sum, k, 64);
    if ((tid & 63) == 0) red[tid >> 6] = sum;
    __syncthreads();
    if (tid == 0) { bd = red[0] + red[1] + red[2] + red[3]; smax[b] = bm; ssum[b] = bd; }
    __syncthreads();
    float invD = 1.f / bd;

    for (int i = start + tid; i < end; i += 256)
        score[i] = __expf(score[i] - M) * invD;
}

// ---------------- finalize: out = fix2float(acc64) / (e^M * D) ----------------
__global__ void finalize_kernel(const unsigned long long* __restrict__ acc64,
                                const float* __restrict__ smax, const float* __restrict__ ssum,
                                float* __restrict__ out) {
    int i = blockIdx.x * 256 + threadIdx.x;
    int b = i >> 10;
    double denom = exp((double)smax[b]) * (double)ssum[b];
    out[i] = (float)(((double)(long long)acc64[i]) * (1.0 / FIX2) / denom);
}

extern "C" void kernel_launch(void* const* d_in, const int* in_sizes, int n_in,
                              void* d_out, int out_size, void* d_ws, size_t ws_size,
                              hipStream_t stream) {
    const float* feat  = (const float*)d_in[0];
    const int*   batch = (const int*)d_in[1];
    const float* Wa = (const float*)d_in[2];
    const float* ba = (const float*)d_in[3];
    const float* Wb = (const float*)d_in[4];
    const float* bb = (const float*)d_in[5];
    const float* Wc = (const float*)d_in[6];
    const float* bc = (const float*)d_in[7];

    float* out_seg = (float*)d_out;                  // B*D
    float* score   = out_seg + (size_t)BSEG * DDIM;  // N (raw s, then softmax in place)
    float* nf      = score + NROWS;                  // N*D

    unsigned short*     wpre  = (unsigned short*)d_ws;                       // 512 KB
    unsigned long long* acc64 = (unsigned long long*)((char*)d_ws + 524288); // 512 KB
    // smax/ssum overlay the wpre region: written after gemm is done with wpre
    float* smax = (float*)d_ws;
    float* ssum = smax + BSEG;

    hipMemsetAsync(acc64, 0, (size_t)BSEG * DDIM * 8, stream);
    wconv_kernel<<<256, 256, 0, stream>>>(Wa, Wb, wpre);
    gemm_kernel<<<NROWS / 64, 512, 0, stream>>>(feat, wpre, ba, bb, Wc, bc, batch,
                                                nf, score, acc64);
    softmax_kernel<<<BSEG, 256, 0, stream>>>(batch, score, smax, ssum);
    finalize_kernel<<<BSEG * DDIM / 256, 256, 0, stream>>>(acc64, smax, ssum, out_seg);
}